// Round 12
// baseline (1573.119 us; speedup 1.0000x reference)
//
#include <hip/hip_runtime.h>

#define TT 2048
#define DD 256

typedef __fp16 half2_t __attribute__((ext_vector_type(2)));
typedef __fp16 half8_t __attribute__((ext_vector_type(8)));
typedef float f32x4_t __attribute__((ext_vector_type(4)));

static __device__ __forceinline__ float fdot2(half2_t a, half2_t b, float c) {
  return __builtin_amdgcn_fdot2(a, b, c, false);
}

static __device__ __forceinline__ float fast_tanh(float y) {
  float e = __builtin_amdgcn_exp2f(y * 2.885390081777927f);  // exp(2y)
  return 1.0f - 2.0f * __builtin_amdgcn_rcpf(e + 1.0f);
}

// All-DPP XOR-involution perms (VALU pipe) — all four HW-validated (R5/R7/R9).
static __device__ __forceinline__ float dpp_xor1(float v) {
  return __builtin_bit_cast(float, __builtin_amdgcn_update_dpp(
      0, __builtin_bit_cast(int, v), 0xB1 /*quad_perm 1,0,3,2*/, 0xF, 0xF, true));
}
static __device__ __forceinline__ float dpp_xor2(float v) {
  return __builtin_bit_cast(float, __builtin_amdgcn_update_dpp(
      0, __builtin_bit_cast(int, v), 0x4E /*quad_perm 2,3,0,1*/, 0xF, 0xF, true));
}
static __device__ __forceinline__ float dpp_xor7(float v) {
  return __builtin_bit_cast(float, __builtin_amdgcn_update_dpp(
      0, __builtin_bit_cast(int, v), 0x141 /*row_half_mirror*/, 0xF, 0xF, true));
}
static __device__ __forceinline__ float dpp_xor8(float v) {
  return __builtin_bit_cast(float, __builtin_amdgcn_update_dpp(
      0, __builtin_bit_cast(int, v), 0x128 /*row_ror:8*/, 0xF, 0xF, true));
}

// ---------------- Phase 1: U = X * B^T  (MFMA), U written into d_out ----------
// R11 version (confirmed ~78 µs, near BW floor): full-N, 512 thr = 8 waves
// (2 waves/SIMD), 1 block/CU, X read once.
#define BST 264
__global__ __launch_bounds__(512, 2) void rnn_u_gemm(
    const float* __restrict__ X, const float* __restrict__ Bm,
    float* __restrict__ U)
{
  extern __shared__ __fp16 bsh[];  // [256][BST]
  const int tid = threadIdx.x;

  { // stage B (f32 -> f16): thread t does row t>>1, k-half (t&1)*128
    const int r = tid >> 1, kh = (tid & 1) << 7;
    const float* br = Bm + r * DD + kh;
    __fp16* dst = bsh + r * BST + kh;
#pragma unroll
    for (int c = 0; c < 16; ++c) {
      float4 v0 = *(const float4*)(br + c * 8);
      float4 v1 = *(const float4*)(br + c * 8 + 4);
      uint4 w;
      w.x = __builtin_bit_cast(unsigned int, __builtin_amdgcn_cvt_pkrtz(v0.x, v0.y));
      w.y = __builtin_bit_cast(unsigned int, __builtin_amdgcn_cvt_pkrtz(v0.z, v0.w));
      w.z = __builtin_bit_cast(unsigned int, __builtin_amdgcn_cvt_pkrtz(v1.x, v1.y));
      w.w = __builtin_bit_cast(unsigned int, __builtin_amdgcn_cvt_pkrtz(v1.z, v1.w));
      *(uint4*)(dst + c * 8) = w;
    }
  }
  __syncthreads();

  const int wv = tid >> 6;           // 8 waves x 32 tokens = 256 tokens/block
  const int l = tid & 63;
  const int l16 = l & 15;
  const int lk = l >> 4;
  const size_t tok0 = (size_t)blockIdx.x * 256 + wv * 32;

  f32x4_t acc[2][16];
#pragma unroll
  for (int m = 0; m < 2; ++m)
#pragma unroll
    for (int n = 0; n < 16; ++n)
      acc[m][n] = (f32x4_t){0.f, 0.f, 0.f, 0.f};

  const float* xA0 = X + (tok0 + l16) * DD + lk * 8;
  const float* xA1 = X + (tok0 + 16 + l16) * DD + lk * 8;

#pragma unroll
  for (int ks = 0; ks < 8; ++ks) {
    float4 a00 = *(const float4*)(xA0 + ks * 32);
    float4 a01 = *(const float4*)(xA0 + ks * 32 + 4);
    float4 a10 = *(const float4*)(xA1 + ks * 32);
    float4 a11 = *(const float4*)(xA1 + ks * 32 + 4);
    half2_t p0 = __builtin_amdgcn_cvt_pkrtz(a00.x, a00.y);
    half2_t p1 = __builtin_amdgcn_cvt_pkrtz(a00.z, a00.w);
    half2_t p2 = __builtin_amdgcn_cvt_pkrtz(a01.x, a01.y);
    half2_t p3 = __builtin_amdgcn_cvt_pkrtz(a01.z, a01.w);
    half2_t r0 = __builtin_amdgcn_cvt_pkrtz(a10.x, a10.y);
    half2_t r1 = __builtin_amdgcn_cvt_pkrtz(a10.z, a10.w);
    half2_t r2 = __builtin_amdgcn_cvt_pkrtz(a11.x, a11.y);
    half2_t r3 = __builtin_amdgcn_cvt_pkrtz(a11.z, a11.w);
    half8_t af0 = {p0[0], p0[1], p1[0], p1[1], p2[0], p2[1], p3[0], p3[1]};
    half8_t af1 = {r0[0], r0[1], r1[0], r1[1], r2[0], r2[1], r3[0], r3[1]};
#pragma unroll
    for (int n = 0; n < 16; ++n) {
      half8_t bf = *(const half8_t*)(bsh + (n * 16 + l16) * BST + ks * 32 + lk * 8);
      acc[0][n] = __builtin_amdgcn_mfma_f32_16x16x32_f16(af0, bf, acc[0][n], 0, 0, 0);
      acc[1][n] = __builtin_amdgcn_mfma_f32_16x16x32_f16(af1, bf, acc[1][n], 0, 0, 0);
    }
  }

  // D layout: col = l&15, row = (l>>4)*4 + r
#pragma unroll
  for (int m = 0; m < 2; ++m) {
    float* ub = U + (tok0 + m * 16 + lk * 4) * DD + l16;
#pragma unroll
    for (int n = 0; n < 16; ++n)
#pragma unroll
      for (int r = 0; r < 4; ++r)
        ub[(size_t)r * DD + n * 16] = acc[m][n][r];
  }
}

// ---------------- Phase 2: sequential scan h_t = tanh(U_t + Lam h_{t-1}) -----
// R9 structure + TWO INDEPENDENT BATCH ROWS PER THREAD (ILP): rows 2bb, 2bb+1
// share the block, the lamw registers, and the barrier. The two dependency
// chains interleave at instruction level, so the ~660-cyc fixed serial cost
// (ds_read latency + butterfly/tanh tail + write->drain->barrier turnaround)
// is paid once per superstep and amortized over 2 rows. (R8's extra *waves*
// couldn't do this: identical phase, same single chain, lockstep barrier.)
__global__ __launch_bounds__(256, 1) void rnn_scan(
    const float* __restrict__ Lm, float* outp /* U in, h out */)
{
  const int bb = blockIdx.x;                     // 64 blocks, rows 2bb & 2bb+1
  const int tid = threadIdx.x;
  const int wid = tid >> 6;
  const int lane = tid & 63;
  const int b0 = lane & 1, b1 = (lane >> 1) & 1, b2 = (lane >> 2) & 1;
  const int b3 = (lane >> 3) & 1, b4 = (lane >> 4) & 1, b5 = (lane >> 5) & 1;
  const int s = lane & 15;                       // k-chunk [s*16, s*16+16)
  const int G = (wid << 2) | (b5 << 1) | b4;
  const int jbase = G << 4;
  const int rmap = (b0 << 3) ^ (b1 << 2) ^ (b2 ? 14 : 0) ^ b3;
  const int j_out = jbase + rmap;

  __shared__ __align__(16) __fp16 hbuf[2][2 * DD];  // [row][parity*256 halves]

  // weights: slot i holds row jbase + (i ^ rmap), k-window [s*16, s*16+16)
  half2_t lamw[16][8];
#pragma unroll
  for (int i = 0; i < 16; ++i) {
    const float* lp = Lm + (jbase + (i ^ rmap)) * DD + s * 16;
#pragma unroll
    for (int c = 0; c < 4; ++c) {
      float4 v = *(const float4*)(lp + c * 4);
      lamw[i][2 * c]     = __builtin_amdgcn_cvt_pkrtz(v.x, v.y);
      lamw[i][2 * c + 1] = __builtin_amdgcn_cvt_pkrtz(v.z, v.w);
    }
  }

  const char* hrdA = (const char*)hbuf[0] + s * 16;
  const char* hrdB = (const char*)hbuf[1] + s * 16;
  // write byte addr of packed dword (j_out even, j_out^1) for b3==0 lanes:
  const int wbyte = ((b0 ^ b2) << 8) + (G << 4) + ((b1 ^ b2) << 3) + (b2 << 2);
  char* hwrA = (char*)hbuf[0] + wbyte;
  char* hwrB = (char*)hbuf[1] + wbyte;

  const size_t obaseA = (size_t)(2 * bb)     * (TT * DD) + j_out;
  const size_t obaseB = (size_t)(2 * bb + 1) * (TT * DD) + j_out;

  // zero parity-0 buffers of both rows (each 512 B = 128 dwords)
  if (tid < 128) ((unsigned int*)hbuf[0])[tid] = 0u;
  else           ((unsigned int*)hbuf[1])[tid - 128] = 0u;
  float upA0 = outp[obaseA + 0 * DD];
  float upA1 = outp[obaseA + 1 * DD];
  float upA2 = outp[obaseA + 2 * DD];
  float upA3 = outp[obaseA + 3 * DD];
  float upB0 = outp[obaseB + 0 * DD];
  float upB1 = outp[obaseB + 1 * DD];
  float upB2 = outp[obaseB + 2 * DD];
  float upB3 = outp[obaseB + 3 * DD];
  __syncthreads();

// dots + select-free {1,2,7,8}-DPP butterfly + tanh for one row (scoped vars)
#define ROWBODY(hv0, hv1, up, hn_out)                                          \
  {                                                                            \
    unsigned int hd[8] = {hv0.x, hv0.y, hv0.z, hv0.w,                          \
                          hv1.x, hv1.y, hv1.z, hv1.w};                         \
    float acc[16];                                                             \
    _Pragma("unroll")                                                          \
    for (int i = 0; i < 16; ++i) {                                             \
      float a = 0.f;                                                           \
      _Pragma("unroll")                                                        \
      for (int q = 0; q < 8; ++q)                                              \
        a = fdot2(lamw[i][q], __builtin_bit_cast(half2_t, hd[q]), a);          \
      acc[i] = a;                                                              \
    }                                                                          \
    float r0 = acc[0] + dpp_xor1(acc[8]);                                      \
    float r1 = acc[1] + dpp_xor1(acc[9]);                                      \
    float r2 = acc[2] + dpp_xor1(acc[10]);                                     \
    float r3 = acc[3] + dpp_xor1(acc[11]);                                     \
    float r4 = acc[4] + dpp_xor1(acc[12]);                                     \
    float r5 = acc[5] + dpp_xor1(acc[13]);                                     \
    float r6 = acc[6] + dpp_xor1(acc[14]);                                     \
    float r7 = acc[7] + dpp_xor1(acc[15]);                                     \
    float s0 = r0 + dpp_xor2(r4);                                              \
    float s1 = r1 + dpp_xor2(r5);                                              \
    float s2 = r2 + dpp_xor2(r6);                                              \
    float s3 = r3 + dpp_xor2(r7);                                              \
    float t0 = s0 + dpp_xor7(s2);                                              \
    float t1 = s1 + dpp_xor7(s3);                                              \
    float pre = t0 + dpp_xor8(t1) + (up);                                      \
    hn_out = fast_tanh(pre);                                                   \
  }

#define STEP(t, upA, upB, p)                                                   \
  {                                                                            \
    uint4 hA0 = *(const uint4*)(hrdA + (p) * 512);                             \
    uint4 hA1 = *(const uint4*)(hrdA + (p) * 512 + 256);                       \
    uint4 hB0 = *(const uint4*)(hrdB + (p) * 512);                             \
    uint4 hB1 = *(const uint4*)(hrdB + (p) * 512 + 256);                       \
    float hnA, hnB;                                                            \
    ROWBODY(hA0, hA1, upA, hnA)                                                \
    ROWBODY(hB0, hB1, upB, hnB)                                                \
    outp[obaseA + (size_t)(t) * DD] = hnA;                                     \
    outp[obaseB + (size_t)(t) * DD] = hnB;                                     \
    float pnA = dpp_xor8(hnA); /* partner row j_out^1 (L(8)=1) */              \
    float pnB = dpp_xor8(hnB);                                                 \
    if (b3 == 0) {                                                             \
      half2_t pkA = __builtin_amdgcn_cvt_pkrtz(hnA, pnA);                      \
      half2_t pkB = __builtin_amdgcn_cvt_pkrtz(hnB, pnB);                      \
      *(unsigned int*)(hwrA + ((p) ^ 1) * 512) =                               \
          __builtin_bit_cast(unsigned int, pkA);                               \
      *(unsigned int*)(hwrB + ((p) ^ 1) * 512) =                               \
          __builtin_bit_cast(unsigned int, pkB);                               \
    }                                                                          \
    { int tn = (t) + 4; tn = tn > TT - 1 ? TT - 1 : tn;                        \
      upA = outp[obaseA + (size_t)tn * DD];                                    \
      upB = outp[obaseB + (size_t)tn * DD]; }                                  \
    __builtin_amdgcn_sched_barrier(0); /* ds_writes stay above */              \
    asm volatile("s_waitcnt lgkmcnt(0)");                                      \
    __builtin_amdgcn_s_barrier();                                              \
    __builtin_amdgcn_sched_barrier(0); /* next ds_reads stay below */          \
  }

  for (int t = 0; t < TT; t += 4) {
    STEP(t + 0, upA0, upB0, 0)
    STEP(t + 1, upA1, upB1, 1)
    STEP(t + 2, upA2, upB2, 0)
    STEP(t + 3, upA3, upB3, 1)
  }
#undef STEP
#undef ROWBODY
}

extern "C" void kernel_launch(void* const* d_in, const int* in_sizes, int n_in,
                              void* d_out, int out_size, void* d_ws, size_t ws_size,
                              hipStream_t stream) {
  const float* X  = (const float*)d_in[0];   // [128, 2048, 256] f32
  const float* Bm = (const float*)d_in[1];   // [256, 256] f32
  const float* Lm = (const float*)d_in[2];   // [256, 256] f32
  float* out = (float*)d_out;                // [128, 2048, 256] f32

  // GEMM dynamic LDS: 256 * BST * 2 = 135168 B (> 64 KB default) — opt in.
  (void)hipFuncSetAttribute((const void*)rnn_u_gemm,
                            hipFuncAttributeMaxDynamicSharedMemorySize,
                            256 * BST * 2);
  hipLaunchKernelGGL(rnn_u_gemm, dim3(1024), dim3(512), 256 * BST * 2, stream,
                     X, Bm, out);
  hipLaunchKernelGGL(rnn_scan, dim3(64), dim3(256), 0, stream, Lm, out);
}

// Round 13
// 954.164 us; speedup vs baseline: 1.6487x; 1.6487x over previous
//
#include <hip/hip_runtime.h>

#define TT 2048
#define DD 256

typedef __fp16 half2_t __attribute__((ext_vector_type(2)));
typedef __fp16 half8_t __attribute__((ext_vector_type(8)));
typedef float f32x4_t __attribute__((ext_vector_type(4)));

static __device__ __forceinline__ float fdot2(half2_t a, half2_t b, float c) {
  return __builtin_amdgcn_fdot2(a, b, c, false);
}

static __device__ __forceinline__ float fast_tanh(float y) {
  float e = __builtin_amdgcn_exp2f(y * 2.885390081777927f);  // exp(2y)
  return 1.0f - 2.0f * __builtin_amdgcn_rcpf(e + 1.0f);
}

// All-DPP XOR-involution perms (VALU pipe) — all four HW-validated (R5/R7/R9).
static __device__ __forceinline__ float dpp_xor1(float v) {
  return __builtin_bit_cast(float, __builtin_amdgcn_update_dpp(
      0, __builtin_bit_cast(int, v), 0xB1 /*quad_perm 1,0,3,2*/, 0xF, 0xF, true));
}
static __device__ __forceinline__ float dpp_xor2(float v) {
  return __builtin_bit_cast(float, __builtin_amdgcn_update_dpp(
      0, __builtin_bit_cast(int, v), 0x4E /*quad_perm 2,3,0,1*/, 0xF, 0xF, true));
}
static __device__ __forceinline__ float dpp_xor7(float v) {
  return __builtin_bit_cast(float, __builtin_amdgcn_update_dpp(
      0, __builtin_bit_cast(int, v), 0x141 /*row_half_mirror*/, 0xF, 0xF, true));
}
static __device__ __forceinline__ float dpp_xor8(float v) {
  return __builtin_bit_cast(float, __builtin_amdgcn_update_dpp(
      0, __builtin_bit_cast(int, v), 0x128 /*row_ror:8*/, 0xF, 0xF, true));
}

// ---------------- Phase 1: U = X * B^T  (MFMA), U written into d_out ----------
// R11 version (confirmed ~78 µs, ~4.9 TB/s effective): full-N (X read once),
// 512 thr = 8 waves (2 waves/SIMD), 1 block/CU, B staged once in 133 KB LDS
// (per-block B re-read is L2-resident, ~free).
#define BST 264
__global__ __launch_bounds__(512, 2) void rnn_u_gemm(
    const float* __restrict__ X, const float* __restrict__ Bm,
    float* __restrict__ U)
{
  extern __shared__ __fp16 bsh[];  // [256][BST]
  const int tid = threadIdx.x;

  { // stage B (f32 -> f16): thread t does row t>>1, k-half (t&1)*128
    const int r = tid >> 1, kh = (tid & 1) << 7;
    const float* br = Bm + r * DD + kh;
    __fp16* dst = bsh + r * BST + kh;
#pragma unroll
    for (int c = 0; c < 16; ++c) {
      float4 v0 = *(const float4*)(br + c * 8);
      float4 v1 = *(const float4*)(br + c * 8 + 4);
      uint4 w;
      w.x = __builtin_bit_cast(unsigned int, __builtin_amdgcn_cvt_pkrtz(v0.x, v0.y));
      w.y = __builtin_bit_cast(unsigned int, __builtin_amdgcn_cvt_pkrtz(v0.z, v0.w));
      w.z = __builtin_bit_cast(unsigned int, __builtin_amdgcn_cvt_pkrtz(v1.x, v1.y));
      w.w = __builtin_bit_cast(unsigned int, __builtin_amdgcn_cvt_pkrtz(v1.z, v1.w));
      *(uint4*)(dst + c * 8) = w;
    }
  }
  __syncthreads();

  const int wv = tid >> 6;           // 8 waves x 32 tokens = 256 tokens/block
  const int l = tid & 63;
  const int l16 = l & 15;
  const int lk = l >> 4;
  const size_t tok0 = (size_t)blockIdx.x * 256 + wv * 32;

  f32x4_t acc[2][16];
#pragma unroll
  for (int m = 0; m < 2; ++m)
#pragma unroll
    for (int n = 0; n < 16; ++n)
      acc[m][n] = (f32x4_t){0.f, 0.f, 0.f, 0.f};

  const float* xA0 = X + (tok0 + l16) * DD + lk * 8;
  const float* xA1 = X + (tok0 + 16 + l16) * DD + lk * 8;

#pragma unroll
  for (int ks = 0; ks < 8; ++ks) {
    float4 a00 = *(const float4*)(xA0 + ks * 32);
    float4 a01 = *(const float4*)(xA0 + ks * 32 + 4);
    float4 a10 = *(const float4*)(xA1 + ks * 32);
    float4 a11 = *(const float4*)(xA1 + ks * 32 + 4);
    half2_t p0 = __builtin_amdgcn_cvt_pkrtz(a00.x, a00.y);
    half2_t p1 = __builtin_amdgcn_cvt_pkrtz(a00.z, a00.w);
    half2_t p2 = __builtin_amdgcn_cvt_pkrtz(a01.x, a01.y);
    half2_t p3 = __builtin_amdgcn_cvt_pkrtz(a01.z, a01.w);
    half2_t r0 = __builtin_amdgcn_cvt_pkrtz(a10.x, a10.y);
    half2_t r1 = __builtin_amdgcn_cvt_pkrtz(a10.z, a10.w);
    half2_t r2 = __builtin_amdgcn_cvt_pkrtz(a11.x, a11.y);
    half2_t r3 = __builtin_amdgcn_cvt_pkrtz(a11.z, a11.w);
    half8_t af0 = {p0[0], p0[1], p1[0], p1[1], p2[0], p2[1], p3[0], p3[1]};
    half8_t af1 = {r0[0], r0[1], r1[0], r1[1], r2[0], r2[1], r3[0], r3[1]};
#pragma unroll
    for (int n = 0; n < 16; ++n) {
      half8_t bf = *(const half8_t*)(bsh + (n * 16 + l16) * BST + ks * 32 + lk * 8);
      acc[0][n] = __builtin_amdgcn_mfma_f32_16x16x32_f16(af0, bf, acc[0][n], 0, 0, 0);
      acc[1][n] = __builtin_amdgcn_mfma_f32_16x16x32_f16(af1, bf, acc[1][n], 0, 0, 0);
    }
  }

  // D layout: col = l&15, row = (l>>4)*4 + r
#pragma unroll
  for (int m = 0; m < 2; ++m) {
    float* ub = U + (tok0 + m * 16 + lk * 4) * DD + l16;
#pragma unroll
    for (int n = 0; n < 16; ++n)
#pragma unroll
      for (int r = 0; r < 4; ++r)
        ub[(size_t)r * DD + n * 16] = acc[m][n][r];
  }
}

// ---------------- Phase 2: sequential scan h_t = tanh(U_t + Lam h_{t-1}) -----
// Best measured structure (R7/R9/R11, ~873 µs = ~1007 cyc/step): one block per
// batch row, 256 threads = 4 waves (1/SIMD), J=16 rows/thread, s=lane&15
// k-chunks of 16, select-free {1,2,7,8}-DPP butterfly (bijective slot map),
// permuted double-buffered h in LDS (2x ds_read_b128/thread, 2-way banks),
// one barrier/step, lgkmcnt-only drain (vmcnt never drained in-loop).
// Breakdown: ~256 issue + ~250 LDS service/latency + ~160 barrier/skew +
// ~130 butterfly/tanh/write tail. Attempts that regressed: +waves (R8),
// chain micro-cuts (R10), 2-rows ILP (R12 — wall = steps x superstep LATENCY).
__global__ __launch_bounds__(256, 1) void rnn_scan(
    const float* __restrict__ Lm, float* outp /* U in, h out */)
{
  const int bb = blockIdx.x;
  const int tid = threadIdx.x;
  const int wid = tid >> 6;
  const int lane = tid & 63;
  const int b0 = lane & 1, b1 = (lane >> 1) & 1, b2 = (lane >> 2) & 1;
  const int b3 = (lane >> 3) & 1, b4 = (lane >> 4) & 1, b5 = (lane >> 5) & 1;
  const int s = lane & 15;                       // k-chunk [s*16, s*16+16)
  const int G = (wid << 2) | (b5 << 1) | b4;
  const int jbase = G << 4;
  const int rmap = (b0 << 3) ^ (b1 << 2) ^ (b2 ? 14 : 0) ^ b3;
  const int j_out = jbase + rmap;

  __shared__ __align__(16) __fp16 hbuf[2 * DD];  // 2 x 512 B, permuted layout

  // weights: slot i holds row jbase + (i ^ rmap), k-window [s*16, s*16+16)
  half2_t lamw[16][8];
#pragma unroll
  for (int i = 0; i < 16; ++i) {
    const float* lp = Lm + (jbase + (i ^ rmap)) * DD + s * 16;
#pragma unroll
    for (int c = 0; c < 4; ++c) {
      float4 v = *(const float4*)(lp + c * 4);
      lamw[i][2 * c]     = __builtin_amdgcn_cvt_pkrtz(v.x, v.y);
      lamw[i][2 * c + 1] = __builtin_amdgcn_cvt_pkrtz(v.z, v.w);
    }
  }

  const char* hrd = (const char*)hbuf + s * 16;
  // write byte addr of packed dword (j_out even, j_out^1) for b3==0 lanes:
  const int wbyte = ((b0 ^ b2) << 8) + (G << 4) + ((b1 ^ b2) << 3) + (b2 << 2);
  char* hwr = (char*)hbuf + wbyte;

  const size_t obase = (size_t)bb * (TT * DD) + j_out;

  if (tid < 128) ((unsigned int*)hbuf)[tid] = 0u;  // zero buf0 (512 B)
  float up0 = outp[obase + 0 * DD];
  float up1 = outp[obase + 1 * DD];
  float up2 = outp[obase + 2 * DD];
  float up3 = outp[obase + 3 * DD];
  __syncthreads();

#define STEP(t, up, p)                                                         \
  {                                                                            \
    uint4 hv0 = *(const uint4*)(hrd + (p) * 512);                              \
    uint4 hv1 = *(const uint4*)(hrd + (p) * 512 + 256);                        \
    unsigned int hd[8] = {hv0.x, hv0.y, hv0.z, hv0.w,                          \
                          hv1.x, hv1.y, hv1.z, hv1.w};                         \
    float acc[16];                                                             \
    _Pragma("unroll")                                                          \
    for (int i = 0; i < 16; ++i) {                                             \
      float a = 0.f;                                                           \
      _Pragma("unroll")                                                        \
      for (int q = 0; q < 8; ++q)                                              \
        a = fdot2(lamw[i][q], __builtin_bit_cast(half2_t, hd[q]), a);          \
      acc[i] = a;                                                              \
    }                                                                          \
    /* select-free butterfly; stage masks {1,2,7,8}, slot bits {8,4,2,1} */    \
    float r0 = acc[0] + dpp_xor1(acc[8]);                                      \
    float r1 = acc[1] + dpp_xor1(acc[9]);                                      \
    float r2 = acc[2] + dpp_xor1(acc[10]);                                     \
    float r3 = acc[3] + dpp_xor1(acc[11]);                                     \
    float r4 = acc[4] + dpp_xor1(acc[12]);                                     \
    float r5 = acc[5] + dpp_xor1(acc[13]);                                     \
    float r6 = acc[6] + dpp_xor1(acc[14]);                                     \
    float r7 = acc[7] + dpp_xor1(acc[15]);                                     \
    float s0 = r0 + dpp_xor2(r4);                                              \
    float s1 = r1 + dpp_xor2(r5);                                              \
    float s2 = r2 + dpp_xor2(r6);                                              \
    float s3 = r3 + dpp_xor2(r7);                                              \
    float t0 = s0 + dpp_xor7(s2);                                              \
    float t1 = s1 + dpp_xor7(s3);                                              \
    float pre = t0 + dpp_xor8(t1) + (up);                                      \
    float hn = fast_tanh(pre);                                                 \
    outp[obase + (size_t)(t) * DD] = hn;                                       \
    float pn = dpp_xor8(hn); /* partner row j_out^1 (L(8)=1) */                \
    if (b3 == 0) {                                                             \
      half2_t pk = __builtin_amdgcn_cvt_pkrtz(hn, pn);                         \
      *(unsigned int*)(hwr + ((p) ^ 1) * 512) =                                \
          __builtin_bit_cast(unsigned int, pk);                                \
    }                                                                          \
    { int tn = (t) + 4; tn = tn > TT - 1 ? TT - 1 : tn;                        \
      up = outp[obase + (size_t)tn * DD]; }                                    \
    __builtin_amdgcn_sched_barrier(0); /* ds_write stays above */              \
    asm volatile("s_waitcnt lgkmcnt(0)");                                      \
    __builtin_amdgcn_s_barrier();                                              \
    __builtin_amdgcn_sched_barrier(0); /* next ds_read stays below */          \
  }

  for (int t = 0; t < TT; t += 4) {
    STEP(t + 0, up0, 0)
    STEP(t + 1, up1, 1)
    STEP(t + 2, up2, 0)
    STEP(t + 3, up3, 1)
  }
#undef STEP
}

extern "C" void kernel_launch(void* const* d_in, const int* in_sizes, int n_in,
                              void* d_out, int out_size, void* d_ws, size_t ws_size,
                              hipStream_t stream) {
  const float* X  = (const float*)d_in[0];   // [128, 2048, 256] f32
  const float* Bm = (const float*)d_in[1];   // [256, 256] f32
  const float* Lm = (const float*)d_in[2];   // [256, 256] f32
  float* out = (float*)d_out;                // [128, 2048, 256] f32

  // GEMM dynamic LDS: 256 * BST * 2 = 135168 B (> 64 KB default) — opt in.
  (void)hipFuncSetAttribute((const void*)rnn_u_gemm,
                            hipFuncAttributeMaxDynamicSharedMemorySize,
                            256 * BST * 2);
  hipLaunchKernelGGL(rnn_u_gemm, dim3(1024), dim3(512), 256 * BST * 2, stream,
                     X, Bm, out);
  hipLaunchKernelGGL(rnn_scan, dim3(128), dim3(256), 0, stream, Lm, out);
}

// Round 14
// 950.322 us; speedup vs baseline: 1.6554x; 1.0040x over previous
//
#include <hip/hip_runtime.h>

#define TT 2048
#define DD 256

typedef __fp16 half2_t __attribute__((ext_vector_type(2)));
typedef __fp16 half8_t __attribute__((ext_vector_type(8)));
typedef float f32x4_t __attribute__((ext_vector_type(4)));

static __device__ __forceinline__ float fdot2(half2_t a, half2_t b, float c) {
  return __builtin_amdgcn_fdot2(a, b, c, false);
}

static __device__ __forceinline__ float fast_tanh(float y) {
  float e = __builtin_amdgcn_exp2f(y * 2.885390081777927f);  // exp(2y)
  return 1.0f - 2.0f * __builtin_amdgcn_rcpf(e + 1.0f);
}

// All-DPP XOR-involution perms (VALU pipe) — all four HW-validated (R5/R7/R9).
static __device__ __forceinline__ float dpp_xor1(float v) {
  return __builtin_bit_cast(float, __builtin_amdgcn_update_dpp(
      0, __builtin_bit_cast(int, v), 0xB1 /*quad_perm 1,0,3,2*/, 0xF, 0xF, true));
}
static __device__ __forceinline__ float dpp_xor2(float v) {
  return __builtin_bit_cast(float, __builtin_amdgcn_update_dpp(
      0, __builtin_bit_cast(int, v), 0x4E /*quad_perm 2,3,0,1*/, 0xF, 0xF, true));
}
static __device__ __forceinline__ float dpp_xor7(float v) {
  return __builtin_bit_cast(float, __builtin_amdgcn_update_dpp(
      0, __builtin_bit_cast(int, v), 0x141 /*row_half_mirror*/, 0xF, 0xF, true));
}
static __device__ __forceinline__ float dpp_xor8(float v) {
  return __builtin_bit_cast(float, __builtin_amdgcn_update_dpp(
      0, __builtin_bit_cast(int, v), 0x128 /*row_ror:8*/, 0xF, 0xF, true));
}

// ---------------- Phase 1: U = X * B^T  (MFMA), U written into d_out ----------
// R11 version (confirmed ~78 µs, ~4.9 TB/s effective): full-N (X read once),
// 512 thr = 8 waves (2 waves/SIMD), 1 block/CU, B staged once in 133 KB LDS.
#define BST 264
__global__ __launch_bounds__(512, 2) void rnn_u_gemm(
    const float* __restrict__ X, const float* __restrict__ Bm,
    float* __restrict__ U)
{
  extern __shared__ __fp16 bsh[];  // [256][BST]
  const int tid = threadIdx.x;

  { // stage B (f32 -> f16): thread t does row t>>1, k-half (t&1)*128
    const int r = tid >> 1, kh = (tid & 1) << 7;
    const float* br = Bm + r * DD + kh;
    __fp16* dst = bsh + r * BST + kh;
#pragma unroll
    for (int c = 0; c < 16; ++c) {
      float4 v0 = *(const float4*)(br + c * 8);
      float4 v1 = *(const float4*)(br + c * 8 + 4);
      uint4 w;
      w.x = __builtin_bit_cast(unsigned int, __builtin_amdgcn_cvt_pkrtz(v0.x, v0.y));
      w.y = __builtin_bit_cast(unsigned int, __builtin_amdgcn_cvt_pkrtz(v0.z, v0.w));
      w.z = __builtin_bit_cast(unsigned int, __builtin_amdgcn_cvt_pkrtz(v1.x, v1.y));
      w.w = __builtin_bit_cast(unsigned int, __builtin_amdgcn_cvt_pkrtz(v1.z, v1.w));
      *(uint4*)(dst + c * 8) = w;
    }
  }
  __syncthreads();

  const int wv = tid >> 6;           // 8 waves x 32 tokens = 256 tokens/block
  const int l = tid & 63;
  const int l16 = l & 15;
  const int lk = l >> 4;
  const size_t tok0 = (size_t)blockIdx.x * 256 + wv * 32;

  f32x4_t acc[2][16];
#pragma unroll
  for (int m = 0; m < 2; ++m)
#pragma unroll
    for (int n = 0; n < 16; ++n)
      acc[m][n] = (f32x4_t){0.f, 0.f, 0.f, 0.f};

  const float* xA0 = X + (tok0 + l16) * DD + lk * 8;
  const float* xA1 = X + (tok0 + 16 + l16) * DD + lk * 8;

#pragma unroll
  for (int ks = 0; ks < 8; ++ks) {
    float4 a00 = *(const float4*)(xA0 + ks * 32);
    float4 a01 = *(const float4*)(xA0 + ks * 32 + 4);
    float4 a10 = *(const float4*)(xA1 + ks * 32);
    float4 a11 = *(const float4*)(xA1 + ks * 32 + 4);
    half2_t p0 = __builtin_amdgcn_cvt_pkrtz(a00.x, a00.y);
    half2_t p1 = __builtin_amdgcn_cvt_pkrtz(a00.z, a00.w);
    half2_t p2 = __builtin_amdgcn_cvt_pkrtz(a01.x, a01.y);
    half2_t p3 = __builtin_amdgcn_cvt_pkrtz(a01.z, a01.w);
    half2_t r0 = __builtin_amdgcn_cvt_pkrtz(a10.x, a10.y);
    half2_t r1 = __builtin_amdgcn_cvt_pkrtz(a10.z, a10.w);
    half2_t r2 = __builtin_amdgcn_cvt_pkrtz(a11.x, a11.y);
    half2_t r3 = __builtin_amdgcn_cvt_pkrtz(a11.z, a11.w);
    half8_t af0 = {p0[0], p0[1], p1[0], p1[1], p2[0], p2[1], p3[0], p3[1]};
    half8_t af1 = {r0[0], r0[1], r1[0], r1[1], r2[0], r2[1], r3[0], r3[1]};
#pragma unroll
    for (int n = 0; n < 16; ++n) {
      half8_t bf = *(const half8_t*)(bsh + (n * 16 + l16) * BST + ks * 32 + lk * 8);
      acc[0][n] = __builtin_amdgcn_mfma_f32_16x16x32_f16(af0, bf, acc[0][n], 0, 0, 0);
      acc[1][n] = __builtin_amdgcn_mfma_f32_16x16x32_f16(af1, bf, acc[1][n], 0, 0, 0);
    }
  }

  // D layout: col = l&15, row = (l>>4)*4 + r
#pragma unroll
  for (int m = 0; m < 2; ++m) {
    float* ub = U + (tok0 + m * 16 + lk * 4) * DD + l16;
#pragma unroll
    for (int n = 0; n < 16; ++n)
#pragma unroll
      for (int r = 0; r < 4; ++r)
        ub[(size_t)r * DD + n * 16] = acc[m][n][r];
  }
}

// ---------------- Phase 2: sequential scan h_t = tanh(U_t + Lam h_{t-1}) -----
// R9/R11 structure. SINGLE isolated change vs R13: step-tail reorder.
// Old tail: tanh -> global store (addr+issue ON the chain) -> pack -> ds_write
//           -> lgkm(0) -> barrier   (ds_write drain overlapped by nothing)
// New tail: tanh -> pack+ds_write (chain) -> global store + U prefetch
//           (issue overlaps the ds_write completion) -> lgkm(0) -> barrier.
// Mechanism: removes ~20-35 cyc of global-op issue from the serial chain and
// hides it under the ds_write latency. (R10 bundled this with two other
// changes + a GEMM regression; never measured in isolation.)
__global__ __launch_bounds__(256, 1) void rnn_scan(
    const float* __restrict__ Lm, float* outp /* U in, h out */)
{
  const int bb = blockIdx.x;
  const int tid = threadIdx.x;
  const int wid = tid >> 6;
  const int lane = tid & 63;
  const int b0 = lane & 1, b1 = (lane >> 1) & 1, b2 = (lane >> 2) & 1;
  const int b3 = (lane >> 3) & 1, b4 = (lane >> 4) & 1, b5 = (lane >> 5) & 1;
  const int s = lane & 15;                       // k-chunk [s*16, s*16+16)
  const int G = (wid << 2) | (b5 << 1) | b4;
  const int jbase = G << 4;
  const int rmap = (b0 << 3) ^ (b1 << 2) ^ (b2 ? 14 : 0) ^ b3;
  const int j_out = jbase + rmap;

  __shared__ __align__(16) __fp16 hbuf[2 * DD];  // 2 x 512 B, permuted layout

  // weights: slot i holds row jbase + (i ^ rmap), k-window [s*16, s*16+16)
  half2_t lamw[16][8];
#pragma unroll
  for (int i = 0; i < 16; ++i) {
    const float* lp = Lm + (jbase + (i ^ rmap)) * DD + s * 16;
#pragma unroll
    for (int c = 0; c < 4; ++c) {
      float4 v = *(const float4*)(lp + c * 4);
      lamw[i][2 * c]     = __builtin_amdgcn_cvt_pkrtz(v.x, v.y);
      lamw[i][2 * c + 1] = __builtin_amdgcn_cvt_pkrtz(v.z, v.w);
    }
  }

  const char* hrd = (const char*)hbuf + s * 16;
  // write byte addr of packed dword (j_out even, j_out^1) for b3==0 lanes:
  const int wbyte = ((b0 ^ b2) << 8) + (G << 4) + ((b1 ^ b2) << 3) + (b2 << 2);
  char* hwr = (char*)hbuf + wbyte;

  const size_t obase = (size_t)bb * (TT * DD) + j_out;

  if (tid < 128) ((unsigned int*)hbuf)[tid] = 0u;  // zero buf0 (512 B)
  float up0 = outp[obase + 0 * DD];
  float up1 = outp[obase + 1 * DD];
  float up2 = outp[obase + 2 * DD];
  float up3 = outp[obase + 3 * DD];
  __syncthreads();

#define STEP(t, up, p)                                                         \
  {                                                                            \
    uint4 hv0 = *(const uint4*)(hrd + (p) * 512);                              \
    uint4 hv1 = *(const uint4*)(hrd + (p) * 512 + 256);                        \
    unsigned int hd[8] = {hv0.x, hv0.y, hv0.z, hv0.w,                          \
                          hv1.x, hv1.y, hv1.z, hv1.w};                         \
    float acc[16];                                                             \
    _Pragma("unroll")                                                          \
    for (int i = 0; i < 16; ++i) {                                             \
      float a = 0.f;                                                           \
      _Pragma("unroll")                                                        \
      for (int q = 0; q < 8; ++q)                                              \
        a = fdot2(lamw[i][q], __builtin_bit_cast(half2_t, hd[q]), a);          \
      acc[i] = a;                                                              \
    }                                                                          \
    /* select-free butterfly; stage masks {1,2,7,8}, slot bits {8,4,2,1} */    \
    float r0 = acc[0] + dpp_xor1(acc[8]);                                      \
    float r1 = acc[1] + dpp_xor1(acc[9]);                                      \
    float r2 = acc[2] + dpp_xor1(acc[10]);                                     \
    float r3 = acc[3] + dpp_xor1(acc[11]);                                     \
    float r4 = acc[4] + dpp_xor1(acc[12]);                                     \
    float r5 = acc[5] + dpp_xor1(acc[13]);                                     \
    float r6 = acc[6] + dpp_xor1(acc[14]);                                     \
    float r7 = acc[7] + dpp_xor1(acc[15]);                                     \
    float s0 = r0 + dpp_xor2(r4);                                              \
    float s1 = r1 + dpp_xor2(r5);                                              \
    float s2 = r2 + dpp_xor2(r6);                                              \
    float s3 = r3 + dpp_xor2(r7);                                              \
    float t0 = s0 + dpp_xor7(s2);                                              \
    float t1 = s1 + dpp_xor7(s3);                                              \
    float pre = t0 + dpp_xor8(t1) + (up);                                      \
    float hn = fast_tanh(pre);                                                 \
    /* chain-critical ds_write FIRST */                                        \
    float pn = dpp_xor8(hn); /* partner row j_out^1 (L(8)=1) */                \
    if (b3 == 0) {                                                             \
      half2_t pk = __builtin_amdgcn_cvt_pkrtz(hn, pn);                         \
      *(unsigned int*)(hwr + ((p) ^ 1) * 512) =                                \
          __builtin_bit_cast(unsigned int, pk);                                \
    }                                                                          \
    __builtin_amdgcn_sched_barrier(0); /* global ops below, ds_write above */  \
    /* off-chain global ops: issue overlaps ds_write drain */                  \
    outp[obase + (size_t)(t) * DD] = hn;                                       \
    { int tn = (t) + 4; tn = tn > TT - 1 ? TT - 1 : tn;                        \
      up = outp[obase + (size_t)tn * DD]; }                                    \
    __builtin_amdgcn_sched_barrier(0); /* keep them before the wait */         \
    asm volatile("s_waitcnt lgkmcnt(0)");                                      \
    __builtin_amdgcn_s_barrier();                                              \
    __builtin_amdgcn_sched_barrier(0); /* next ds_read stays below */          \
  }

  for (int t = 0; t < TT; t += 4) {
    STEP(t + 0, up0, 0)
    STEP(t + 1, up1, 1)
    STEP(t + 2, up2, 0)
    STEP(t + 3, up3, 1)
  }
#undef STEP
}

extern "C" void kernel_launch(void* const* d_in, const int* in_sizes, int n_in,
                              void* d_out, int out_size, void* d_ws, size_t ws_size,
                              hipStream_t stream) {
  const float* X  = (const float*)d_in[0];   // [128, 2048, 256] f32
  const float* Bm = (const float*)d_in[1];   // [256, 256] f32
  const float* Lm = (const float*)d_in[2];   // [256, 256] f32
  float* out = (float*)d_out;                // [128, 2048, 256] f32

  // GEMM dynamic LDS: 256 * BST * 2 = 135168 B (> 64 KB default) — opt in.
  (void)hipFuncSetAttribute((const void*)rnn_u_gemm,
                            hipFuncAttributeMaxDynamicSharedMemorySize,
                            256 * BST * 2);
  hipLaunchKernelGGL(rnn_u_gemm, dim3(1024), dim3(512), 256 * BST * 2, stream,
                     X, Bm, out);
  hipLaunchKernelGGL(rnn_scan, dim3(128), dim3(256), 0, stream, Lm, out);
}